// Round 23
// baseline (150.673 us; speedup 1.0000x reference)
//
#include <hip/hip_runtime.h>
#include <hip/hip_fp16.h>

// GCN: 2x GCNConv (5->16->32) + global mean pool + linear head.
// v22: v21 with the build pipeline collapsed: count+scan+scatter merged into
// ONE k_bin (per-block LDS histogram -> one global atomicAdd per non-empty
// bucket for the exact segment base -> LDS-staged bucket-sorted burst write).
// Deletes k_cnt's full dst pass, the blkcnt/base matrices, and 2 launches.
// Segment order within a bucket becomes timing-dependent (fp reorder ~1e-7,
// far under threshold; v1-v11 had the same property). k_zero (1 tiny launch)
// zeroes bcursor/pool/gcnt. Gathers/lin/fin identical to v21.

#define RANGE 256          // nodes per bucket (d>>8)
#define NB 391             // ceil(100000/256)
#define RPB (RANGE + 1)    // rowp entries per bucket (incl. end)
#define CAP 10240          // record capacity per bucket (exact fill ~8184+-90)
#define NBLK 512           // edge-pass blocks
#define CHUNKMAX 6400      // >= ceil(E/NBLK) = 6250
#define PSPREAD 8

// zero bcursor + pool + gcnt (replaces memsets; poisoned workspace otherwise)
__global__ void k_zero(int* __restrict__ bcursor, int* __restrict__ poolgc, int nz) {
    int t = blockIdx.x * blockDim.x + threadIdx.x;
    if (t < NB) bcursor[t] = 0;
    if (t < nz) poolgc[t] = 0;
}

// merged binning: histogram -> atomic segment base -> staged burst scatter.
// rec = (src<<8) | dst_local, grouped by bucket in recbuf[b*CAP ...].
__global__ __launch_bounds__(512) void k_bin(const int* __restrict__ src,
        const int* __restrict__ dst, int E, int chunk,
        int* __restrict__ bcursor, unsigned int* __restrict__ recbuf) {
    __shared__ unsigned int lbuf[CHUNKMAX];
    __shared__ unsigned short bkt[CHUNKMAX];
    __shared__ int h[NB], lsc[NB], h2[NB], base_l[NB];
    __shared__ int sc[512];
    int t = threadIdx.x;
    if (t < NB) { h[t] = 0; h2[t] = 0; }
    __syncthreads();
    int e0 = blockIdx.x * chunk;
    int e1 = min(e0 + chunk, E);
    int len = e1 - e0;
    for (int e = e0 + t; e < e1; e += 512)
        atomicAdd(&h[__builtin_nontemporal_load(dst + e) >> 8], 1);
    __syncthreads();
    int v = (t < NB) ? h[t] : 0;
    sc[t] = v;
    __syncthreads();
    for (int off = 1; off < 512; off <<= 1) {
        int u = (t >= off) ? sc[t - off] : 0;
        __syncthreads();
        sc[t] += u;
        __syncthreads();
    }
    if (t < NB) {
        lsc[t] = sc[t] - v;
        base_l[t] = v ? t * CAP + atomicAdd(&bcursor[t], v) : 0;  // exact segment
    }
    __syncthreads();
    for (int e = e0 + t; e < e1; e += 512) {
        int d = __builtin_nontemporal_load(dst + e);
        int s = __builtin_nontemporal_load(src + e);
        int b = d >> 8;
        int r = atomicAdd(&h2[b], 1);
        int pos = lsc[b] + r;
        lbuf[pos] = ((unsigned)s << 8) | (unsigned)(d & 255);
        bkt[pos] = (unsigned short)b;
    }
    __syncthreads();
    for (int i = t; i < len; i += 512) {
        int b = bkt[i];
        recbuf[base_l[b] + (i - lsc[b])] = lbuf[i];  // burst per segment
    }
}

// per-bucket LDS counting sort by dst_local; cnt[] doubles as degree, so
// dinv and the fp16 pair-packed sx8 row are computed here too (fused prep).
// bfill == bcursor (final totals). Block 0 thread 0 writes sx8's zero row N.
__global__ __launch_bounds__(512) void k_sort(const int* __restrict__ bfill,
        const unsigned int* __restrict__ recbuf, int* __restrict__ rowp,
        int* __restrict__ srt, const float* __restrict__ x,
        float* __restrict__ dinv, __half* __restrict__ sx8, int N) {
    __shared__ int cnt[RANGE], lbase[RANGE], rank[RANGE], sc[RANGE];
    int b = blockIdx.x;
    int t = threadIdx.x;
    if (t < RANGE) { cnt[t] = 0; rank[t] = 0; }
    if (b == 0 && t == 0) {
        uint4 z = {0u, 0u, 0u, 0u};
        *(uint4*)(sx8 + (size_t)N * 8) = z;     // zero row N
    }
    __syncthreads();
    int len = bfill[b];
    int g0 = b * CAP;
    const unsigned* rb = recbuf + (size_t)g0;
    for (int r = t; r < len; r += 512)
        atomicAdd(&cnt[__builtin_nontemporal_load(rb + r) & 255], 1);
    __syncthreads();
    if (t < RANGE) sc[t] = cnt[t];
    __syncthreads();
    for (int off = 1; off < RANGE; off <<= 1) {
        int u = 0;
        if (t < RANGE && t >= off) u = sc[t - off];
        __syncthreads();
        if (t < RANGE) sc[t] += u;
        __syncthreads();
    }
    if (t < RANGE) {
        lbase[t] = sc[t] - cnt[t];
        rowp[b * RPB + t] = g0 + lbase[t];
        if (t == RANGE - 1) rowp[b * RPB + RANGE] = g0 + sc[t];
        int i = b * RANGE + t;
        if (i < N) {
            float di = rsqrtf((float)(cnt[t] + 1));
            dinv[i] = di;
            union { __half h[8]; uint4 u; } pk;
#pragma unroll
            for (int d = 0; d < 5; ++d) pk.h[d] = __float2half(x[i * 5 + d] * di);
            pk.h[5] = __float2half(0.f); pk.h[6] = __float2half(0.f); pk.h[7] = __float2half(0.f);
            *(uint4*)(sx8 + (size_t)i * 8) = pk.u;
        }
    }
    __syncthreads();
    for (int r = t; r < len; r += 512) {
        unsigned rec = __builtin_nontemporal_load(rb + r);
        int key = (int)(rec & 255);
        int pos = g0 + lbase[key] + atomicAdd(&rank[key], 1);
        srt[pos] = (int)(rec >> 8);   // plain store: L2-merged in bucket slice
    }
}

// TWO nodes per wave (32 lanes each). Per half: lane k2 in [0,4) owns feature
// pair (2k2,2k2+1); j in [0,8) slots; depth 4 -> 32 edges per round. Tail
// slots clamp to zeroed row N. Reduce: xor 4,8,16 (stays within the half).
__global__ void k_gather8(const int* __restrict__ rowp, const int* __restrict__ srt,
                          const __half* __restrict__ sx8, float* __restrict__ agg8, int N) {
    int wv = (blockIdx.x * blockDim.x + threadIdx.x) >> 6;
    int lane = threadIdx.x & 63;
    int hl = lane & 31;
    int node = wv * 2 + (lane >> 5);
    if (node >= N) return;
    int k2 = hl & 3, j = hl >> 2;
    int b = node >> 8, dl = node & 255;
    int base = b * RPB + dl;
    int p0 = rowp[base], p1 = rowp[base + 1];
    const __half2* tab = (const __half2*)sx8;   // row = 4 half2s
    float ax = 0.f, ay = 0.f;
    int p = p0 + j;
    while (p < p1) {
        int s0 = __builtin_nontemporal_load(srt + p);
        int s1 = __builtin_nontemporal_load(srt + p + 8);
        int s2 = __builtin_nontemporal_load(srt + p + 16);
        int s3 = __builtin_nontemporal_load(srt + p + 24);
        s1 = (p + 8  < p1) ? s1 : N;
        s2 = (p + 16 < p1) ? s2 : N;
        s3 = (p + 24 < p1) ? s3 : N;
        float2 f0 = __half22float2(tab[(size_t)s0 * 4 + k2]);
        float2 f1 = __half22float2(tab[(size_t)s1 * 4 + k2]);
        float2 f2 = __half22float2(tab[(size_t)s2 * 4 + k2]);
        float2 f3 = __half22float2(tab[(size_t)s3 * 4 + k2]);
        ax += (f0.x + f1.x) + (f2.x + f3.x);
        ay += (f0.y + f1.y) + (f2.y + f3.y);
        p += 32;
    }
    ax += __shfl_xor(ax, 4, 64);
    ax += __shfl_xor(ax, 8, 64);
    ax += __shfl_xor(ax, 16, 64);
    ay += __shfl_xor(ay, 4, 64);
    ay += __shfl_xor(ay, 8, 64);
    ay += __shfl_xor(ay, 16, 64);
    if (hl < 4) {
        float2 self = __half22float2(tab[(size_t)node * 4 + k2]);   // self-loop
        agg8[(size_t)node * 8 + 2 * k2]     = ax + self.x;
        agg8[(size_t)node * 8 + 2 * k2 + 1] = ay + self.y;
    }
}

// h1 = relu(dinv*(agg8[:5]@W1) + b1); g = dinv*h1 (16), stored fp16.
// thread i==N writes the zero row (tail target for gather16).
__global__ void k_lin1(const float* __restrict__ agg8, const float* __restrict__ dinv,
                       const float* __restrict__ W1, const float* __restrict__ b1,
                       __half* __restrict__ g, int N) {
    __shared__ float sW[80], sb[16];
    if (threadIdx.x < 80) sW[threadIdx.x] = W1[threadIdx.x];
    if (threadIdx.x < 16) sb[threadIdx.x] = b1[threadIdx.x];
    __syncthreads();
    int i = blockIdx.x * blockDim.x + threadIdx.x;
    if (i > N) return;
    uint4* gp = (uint4*)(g + (size_t)i * 16);   // 32B row
    if (i == N) {
        uint4 z = {0u, 0u, 0u, 0u};
        gp[0] = z; gp[1] = z;
        return;
    }
    float di = dinv[i];
    const float4* a4 = (const float4*)(agg8 + (size_t)i * 8);
    float4 v0 = a4[0], v1 = a4[1];
    float a[5] = {v0.x, v0.y, v0.z, v0.w, v1.x};
    union { __half h[16]; uint4 u[2]; } pk;
#pragma unroll
    for (int kk = 0; kk < 16; ++kk) {
        float h = 0.f;
#pragma unroll
        for (int d = 0; d < 5; ++d) h = fmaf(a[d], sW[d * 16 + kk], h);
        h = fmaxf(fmaf(di, h, sb[kk]), 0.f);
        pk.h[kk] = __float2half(h * di);
    }
    gp[0] = pk.u[0];
    gp[1] = pk.u[1];
}

// TWO nodes per wave (32 lanes each). Per half: lane k in [0,8) owns feature
// pair (2k,2k+1); j in [0,4) slots; depth 8 -> 32 edges per round. Tail slots
// clamp to zeroed row N. Reduce: xor 8,16 (stays within the half).
__global__ void k_gather16(const int* __restrict__ rowp, const int* __restrict__ srt,
                           const __half* __restrict__ g, float* __restrict__ agg16, int N) {
    int wv = (blockIdx.x * blockDim.x + threadIdx.x) >> 6;
    int lane = threadIdx.x & 63;
    int hl = lane & 31;
    int node = wv * 2 + (lane >> 5);
    if (node >= N) return;
    int k = hl & 7, j = hl >> 3;
    int b = node >> 8, dl = node & 255;
    int base = b * RPB + dl;
    int p0 = rowp[base], p1 = rowp[base + 1];
    const __half2* gp = (const __half2*)g;      // row = 8 half2s
    float ax = 0.f, ay = 0.f;
    int p = p0 + j;
    while (p < p1) {
        int s0 = __builtin_nontemporal_load(srt + p);
        int s1 = __builtin_nontemporal_load(srt + p + 4);
        int s2 = __builtin_nontemporal_load(srt + p + 8);
        int s3 = __builtin_nontemporal_load(srt + p + 12);
        int s4 = __builtin_nontemporal_load(srt + p + 16);
        int s5 = __builtin_nontemporal_load(srt + p + 20);
        int s6 = __builtin_nontemporal_load(srt + p + 24);
        int s7 = __builtin_nontemporal_load(srt + p + 28);
        s1 = (p + 4  < p1) ? s1 : N;
        s2 = (p + 8  < p1) ? s2 : N;
        s3 = (p + 12 < p1) ? s3 : N;
        s4 = (p + 16 < p1) ? s4 : N;
        s5 = (p + 20 < p1) ? s5 : N;
        s6 = (p + 24 < p1) ? s6 : N;
        s7 = (p + 28 < p1) ? s7 : N;
        float2 f0 = __half22float2(gp[(size_t)s0 * 8 + k]);
        float2 f1 = __half22float2(gp[(size_t)s1 * 8 + k]);
        float2 f2 = __half22float2(gp[(size_t)s2 * 8 + k]);
        float2 f3 = __half22float2(gp[(size_t)s3 * 8 + k]);
        float2 f4 = __half22float2(gp[(size_t)s4 * 8 + k]);
        float2 f5 = __half22float2(gp[(size_t)s5 * 8 + k]);
        float2 f6 = __half22float2(gp[(size_t)s6 * 8 + k]);
        float2 f7 = __half22float2(gp[(size_t)s7 * 8 + k]);
        ax += ((f0.x + f1.x) + (f2.x + f3.x)) + ((f4.x + f5.x) + (f6.x + f7.x));
        ay += ((f0.y + f1.y) + (f2.y + f3.y)) + ((f4.y + f5.y) + (f6.y + f7.y));
        p += 32;
    }
    ax += __shfl_xor(ax, 8, 64);
    ax += __shfl_xor(ax, 16, 64);
    ay += __shfl_xor(ay, 8, 64);
    ay += __shfl_xor(ay, 16, 64);
    if (hl < 8) {
        float2 self = __half22float2(gp[(size_t)node * 8 + k]);   // self-loop
        agg16[(size_t)node * 16 + 2 * k]     = ax + self.x;
        agg16[(size_t)node * 16 + 2 * k + 1] = ay + self.y;
    }
}

// h2 = relu(dinv*(agg16@W2) + b2); c = h2 . fcW; spread-8 pool atomics
__global__ void k_fin(const float* __restrict__ agg16, const float* __restrict__ dinv,
                      const float* __restrict__ W2, const float* __restrict__ b2,
                      const float* __restrict__ fcW, const int* __restrict__ batch,
                      float* __restrict__ pool, int* __restrict__ gcnt, int N, int G) {
    __shared__ float sW[512], sb[32], sf[32];
    for (int t = threadIdx.x; t < 512; t += blockDim.x) sW[t] = W2[t];
    if (threadIdx.x < 32) {
        sb[threadIdx.x] = b2[threadIdx.x];
        sf[threadIdx.x] = fcW[threadIdx.x];
    }
    __syncthreads();
    int i = blockIdx.x * blockDim.x + threadIdx.x;
    if (i >= N) return;
    float di = dinv[i];
    float a[16];
    const float4* a4 = (const float4*)(agg16 + (size_t)i * 16);
#pragma unroll
    for (int q = 0; q < 4; ++q) {
        float4 v = a4[q];
        a[q * 4 + 0] = v.x; a[q * 4 + 1] = v.y; a[q * 4 + 2] = v.z; a[q * 4 + 3] = v.w;
    }
    float c = 0.f;
#pragma unroll
    for (int jj = 0; jj < 32; ++jj) {
        float acc2 = 0.f;
#pragma unroll
        for (int kk = 0; kk < 16; ++kk) acc2 = fmaf(a[kk], sW[kk * 32 + jj], acc2);
        float h = fmaxf(fmaf(di, acc2, sb[jj]), 0.f);
        c = fmaf(h, sf[jj], c);
    }
    int bidx = batch[i];
    int slot = i & (PSPREAD - 1);
    atomicAdd(&pool[slot * G + bidx], c);
    atomicAdd(&gcnt[slot * G + bidx], 1);
}

__global__ void k_out(const float* __restrict__ pool, const int* __restrict__ gcnt,
                      const float* __restrict__ fcb, float* __restrict__ out, int G) {
    int gI = blockIdx.x * blockDim.x + threadIdx.x;
    if (gI >= G) return;
    float s = 0.f; int c = 0;
#pragma unroll
    for (int k = 0; k < PSPREAD; ++k) { s += pool[k * G + gI]; c += gcnt[k * G + gI]; }
    out[gI] = s / fmaxf((float)c, 1.f) + fcb[0];
}

extern "C" void kernel_launch(void* const* d_in, const int* in_sizes, int n_in,
                              void* d_out, int out_size, void* d_ws, size_t ws_size,
                              hipStream_t stream) {
    const float* x    = (const float*)d_in[0];
    const int*   ei   = (const int*)d_in[1];
    const int*   batch= (const int*)d_in[2];
    const float* W1   = (const float*)d_in[3];
    const float* b1   = (const float*)d_in[4];
    const float* W2   = (const float*)d_in[5];
    const float* b2   = (const float*)d_in[6];
    const float* fcW  = (const float*)d_in[7];
    const float* fcb  = (const float*)d_in[8];
    float* out = (float*)d_out;

    const int N = in_sizes[0] / 5;
    const int E = in_sizes[1] / 2;
    const int G = out_size;  // 1024
    const int chunk = (E + NBLK - 1) / NBLK;  // 6250 <= CHUNKMAX

    const int* src = ei;
    const int* dst = ei + E;

    // workspace carve, every buffer 256B-aligned
    char* ws = (char*)d_ws;
    size_t o = 0;
    auto carve = [&](size_t bytes) -> char* {
        char* p = ws + o;
        o += (bytes + 255) & ~(size_t)255;
        return p;
    };
    int*    bcursor = (int*)carve((size_t)4 * NB);               // doubles as bfill
    int*    rowp    = (int*)carve((size_t)4 * (NB * RPB + 4));
    float*  dinv    = (float*)carve((size_t)4 * N);
    __half* sx8     = (__half*)carve((size_t)16 * (N + 1));      // fp16 rows + zero row
    float*  agg8    = (float*)carve((size_t)32 * N);             // 3.2 MB
    int*    srt     = (int*)carve((size_t)4 * NB * CAP + 256);   // 16 MB + pad
    char*   rbase   = carve((size_t)4 * NB * CAP);               // 16 MB
    unsigned int* recbuf = (unsigned int*)rbase;                 // dead after k_sort
    __half* g       = (__half*)rbase;                            // (N+1) x 16 halves, post-k_sort
    float*  agg16   = (float*)(rbase + (((size_t)32 * (N + 1) + 255) & ~(size_t)255)); // N x 16 f32
    float*  pool    = (float*)carve((size_t)4 * PSPREAD * G);
    int*    gcnt    = (int*)carve((size_t)4 * PSPREAD * G);      // contiguous with pool

    const int nz = 2 * PSPREAD * G;   // pool + gcnt ints

    k_zero<<<(nz + 255) / 256, 256, 0, stream>>>(bcursor, (int*)pool, nz);
    k_bin<<<NBLK, 512, 0, stream>>>(src, dst, E, chunk, bcursor, recbuf);
    k_sort<<<NB, 512, 0, stream>>>(bcursor, recbuf, rowp, srt, x, dinv, sx8, N);
    {
        long long waves = (N + 1) / 2;
        int blocks = (int)((waves * 64 + 255) / 256);
        k_gather8<<<blocks, 256, 0, stream>>>(rowp, srt, sx8, agg8, N);
    }
    k_lin1<<<(N + 256) / 256, 256, 0, stream>>>(agg8, dinv, W1, b1, g, N);
    {
        long long waves = (N + 1) / 2;
        int blocks = (int)((waves * 64 + 255) / 256);
        k_gather16<<<blocks, 256, 0, stream>>>(rowp, srt, g, agg16, N);
    }
    k_fin<<<(N + 255) / 256, 256, 0, stream>>>(agg16, dinv, W2, b2, fcW, batch, pool, gcnt, N, G);
    k_out<<<(G + 255) / 256, 256, 0, stream>>>(pool, gcnt, fcb, out, G);
}

// Round 24
// 143.939 us; speedup vs baseline: 1.0468x; 1.0468x over previous
//
#include <hip/hip_runtime.h>
#include <hip/hip_fp16.h>

// GCN: 2x GCNConv (5->16->32) + global mean pool + linear head.
// v23: build pipeline reverted to v21's split count->scan->scatter (v22's
// merged k_bin serialized its phases: +5us). gather16 re-tiled: lane owns a
// feature QUAD via one 8B uint2 load (2x half2) -> 4 quad-lanes x 8 slots x
// depth 4 = 32 edges per round at 8 VMEM ops/lane (half of v21's 16).
// Everything else identical to v21 (two nodes/wave, fp16 tables, zero-row
// tails, fused zeroing in k_cnt, fused prep in k_sort).

#define RANGE 256          // nodes per bucket (d>>8)
#define NB 391             // ceil(100000/256)
#define RPB (RANGE + 1)    // rowp entries per bucket (incl. end)
#define CAP 10240          // record capacity per bucket (exact fill ~8184+-90)
#define NBLK 512           // edge-pass blocks
#define CHUNKMAX 6400      // >= ceil(E/NBLK) = 6250
#define PSPREAD 8

// per-block LDS histogram of dst buckets -> blkcnt[blk][NB]; also zeroes
// pool/gcnt (grid-stride store, replaces hipMemsetAsync).
__global__ void k_cnt(const int* __restrict__ dst, int E, int chunk,
                      int* __restrict__ blkcnt, int* __restrict__ poolgc, int nz) {
    int z = blockIdx.x * blockDim.x + threadIdx.x;
    if (z < nz) poolgc[z] = 0;
    __shared__ int h[NB];
    for (int t = threadIdx.x; t < NB; t += blockDim.x) h[t] = 0;
    __syncthreads();
    int e0 = blockIdx.x * chunk;
    int e1 = min(e0 + chunk, E);
    for (int e = e0 + threadIdx.x; e < e1; e += blockDim.x)
        atomicAdd(&h[dst[e] >> 8], 1);
    __syncthreads();
    int* row = blkcnt + (size_t)blockIdx.x * NB;
    for (int t = threadIdx.x; t < NB; t += blockDim.x) row[t] = h[t];
}

// one block per bucket: exclusive scan over the NBLK per-block counts.
__global__ __launch_bounds__(512) void k_scanb(const int* __restrict__ blkcnt,
        int* __restrict__ base, int* __restrict__ bfill) {
    __shared__ int part[NBLK];
    int b = blockIdx.x, t = threadIdx.x;   // NBLK == 512 threads
    int v = blkcnt[(size_t)t * NB + b];    // column read, L2-cached
    part[t] = v;
    __syncthreads();
    for (int off = 1; off < NBLK; off <<= 1) {
        int u = (t >= off) ? part[t - off] : 0;
        __syncthreads();
        part[t] += u;
        __syncthreads();
    }
    base[(size_t)b * NBLK + t] = b * CAP + part[t] - v;  // coalesced row write
    if (t == NBLK - 1) bfill[b] = part[t];
}

// scatter records at exact offsets, via LDS staging sorted by bucket, then
// burst writes (consecutive lanes -> consecutive addresses per segment).
__global__ __launch_bounds__(512) void k_scat(const int* __restrict__ src,
        const int* __restrict__ dst, int E, int chunk,
        const int* __restrict__ base, unsigned int* __restrict__ recbuf) {
    __shared__ unsigned int lbuf[CHUNKMAX];
    __shared__ unsigned short bkt[CHUNKMAX];
    __shared__ int h[NB], lsc[NB], h2[NB], base_l[NB];
    __shared__ int sc[512];
    int t = threadIdx.x;
    if (t < NB) { h[t] = 0; h2[t] = 0; }
    __syncthreads();
    int e0 = blockIdx.x * chunk;
    int e1 = min(e0 + chunk, E);
    int len = e1 - e0;
    for (int e = e0 + t; e < e1; e += 512)
        atomicAdd(&h[__builtin_nontemporal_load(dst + e) >> 8], 1);
    __syncthreads();
    int v = (t < NB) ? h[t] : 0;
    sc[t] = v;
    __syncthreads();
    for (int off = 1; off < 512; off <<= 1) {
        int u = (t >= off) ? sc[t - off] : 0;
        __syncthreads();
        sc[t] += u;
        __syncthreads();
    }
    if (t < NB) {
        lsc[t] = sc[t] - v;
        base_l[t] = base[(size_t)t * NBLK + blockIdx.x];  // column read, L2-cached
    }
    __syncthreads();
    for (int e = e0 + t; e < e1; e += 512) {
        int d = __builtin_nontemporal_load(dst + e);
        int s = __builtin_nontemporal_load(src + e);
        int b = d >> 8;
        int r = atomicAdd(&h2[b], 1);
        int pos = lsc[b] + r;
        lbuf[pos] = ((unsigned)s << 8) | (unsigned)(d & 255);
        bkt[pos] = (unsigned short)b;
    }
    __syncthreads();
    for (int i = t; i < len; i += 512) {
        int b = bkt[i];
        recbuf[base_l[b] + (i - lsc[b])] = lbuf[i];  // burst per segment
    }
}

// per-bucket LDS counting sort by dst_local; cnt[] doubles as degree, so
// dinv and the fp16 pair-packed sx8 row are computed here too (fused prep).
// Block 0 thread 0 also writes sx8's zero row N (gather8 tail target).
__global__ __launch_bounds__(512) void k_sort(const int* __restrict__ bfill,
        const unsigned int* __restrict__ recbuf, int* __restrict__ rowp,
        int* __restrict__ srt, const float* __restrict__ x,
        float* __restrict__ dinv, __half* __restrict__ sx8, int N) {
    __shared__ int cnt[RANGE], lbase[RANGE], rank[RANGE], sc[RANGE];
    int b = blockIdx.x;
    int t = threadIdx.x;
    if (t < RANGE) { cnt[t] = 0; rank[t] = 0; }
    if (b == 0 && t == 0) {
        uint4 z = {0u, 0u, 0u, 0u};
        *(uint4*)(sx8 + (size_t)N * 8) = z;     // zero row N
    }
    __syncthreads();
    int len = bfill[b];
    int g0 = b * CAP;
    const unsigned* rb = recbuf + (size_t)g0;
    for (int r = t; r < len; r += 512)
        atomicAdd(&cnt[__builtin_nontemporal_load(rb + r) & 255], 1);
    __syncthreads();
    if (t < RANGE) sc[t] = cnt[t];
    __syncthreads();
    for (int off = 1; off < RANGE; off <<= 1) {
        int u = 0;
        if (t < RANGE && t >= off) u = sc[t - off];
        __syncthreads();
        if (t < RANGE) sc[t] += u;
        __syncthreads();
    }
    if (t < RANGE) {
        lbase[t] = sc[t] - cnt[t];
        rowp[b * RPB + t] = g0 + lbase[t];
        if (t == RANGE - 1) rowp[b * RPB + RANGE] = g0 + sc[t];
        int i = b * RANGE + t;
        if (i < N) {
            float di = rsqrtf((float)(cnt[t] + 1));
            dinv[i] = di;
            union { __half h[8]; uint4 u; } pk;
#pragma unroll
            for (int d = 0; d < 5; ++d) pk.h[d] = __float2half(x[i * 5 + d] * di);
            pk.h[5] = __float2half(0.f); pk.h[6] = __float2half(0.f); pk.h[7] = __float2half(0.f);
            *(uint4*)(sx8 + (size_t)i * 8) = pk.u;
        }
    }
    __syncthreads();
    for (int r = t; r < len; r += 512) {
        unsigned rec = __builtin_nontemporal_load(rb + r);
        int key = (int)(rec & 255);
        int pos = g0 + lbase[key] + atomicAdd(&rank[key], 1);
        srt[pos] = (int)(rec >> 8);   // plain store: L2-merged in bucket slice
    }
}

// TWO nodes per wave (32 lanes each). Per half: lane k2 in [0,4) owns feature
// pair (2k2,2k2+1); j in [0,8) slots; depth 4 -> 32 edges per round. Tail
// slots clamp to zeroed row N. Reduce: xor 4,8,16 (stays within the half).
__global__ void k_gather8(const int* __restrict__ rowp, const int* __restrict__ srt,
                          const __half* __restrict__ sx8, float* __restrict__ agg8, int N) {
    int wv = (blockIdx.x * blockDim.x + threadIdx.x) >> 6;
    int lane = threadIdx.x & 63;
    int hl = lane & 31;
    int node = wv * 2 + (lane >> 5);
    if (node >= N) return;
    int k2 = hl & 3, j = hl >> 2;
    int b = node >> 8, dl = node & 255;
    int base = b * RPB + dl;
    int p0 = rowp[base], p1 = rowp[base + 1];
    const __half2* tab = (const __half2*)sx8;   // row = 4 half2s
    float ax = 0.f, ay = 0.f;
    int p = p0 + j;
    while (p < p1) {
        int s0 = __builtin_nontemporal_load(srt + p);
        int s1 = __builtin_nontemporal_load(srt + p + 8);
        int s2 = __builtin_nontemporal_load(srt + p + 16);
        int s3 = __builtin_nontemporal_load(srt + p + 24);
        s1 = (p + 8  < p1) ? s1 : N;
        s2 = (p + 16 < p1) ? s2 : N;
        s3 = (p + 24 < p1) ? s3 : N;
        float2 f0 = __half22float2(tab[(size_t)s0 * 4 + k2]);
        float2 f1 = __half22float2(tab[(size_t)s1 * 4 + k2]);
        float2 f2 = __half22float2(tab[(size_t)s2 * 4 + k2]);
        float2 f3 = __half22float2(tab[(size_t)s3 * 4 + k2]);
        ax += (f0.x + f1.x) + (f2.x + f3.x);
        ay += (f0.y + f1.y) + (f2.y + f3.y);
        p += 32;
    }
    ax += __shfl_xor(ax, 4, 64);
    ax += __shfl_xor(ax, 8, 64);
    ax += __shfl_xor(ax, 16, 64);
    ay += __shfl_xor(ay, 4, 64);
    ay += __shfl_xor(ay, 8, 64);
    ay += __shfl_xor(ay, 16, 64);
    if (hl < 4) {
        float2 self = __half22float2(tab[(size_t)node * 4 + k2]);   // self-loop
        agg8[(size_t)node * 8 + 2 * k2]     = ax + self.x;
        agg8[(size_t)node * 8 + 2 * k2 + 1] = ay + self.y;
    }
}

// h1 = relu(dinv*(agg8[:5]@W1) + b1); g = dinv*h1 (16), stored fp16.
// thread i==N writes the zero row (tail target for gather16).
__global__ void k_lin1(const float* __restrict__ agg8, const float* __restrict__ dinv,
                       const float* __restrict__ W1, const float* __restrict__ b1,
                       __half* __restrict__ g, int N) {
    __shared__ float sW[80], sb[16];
    if (threadIdx.x < 80) sW[threadIdx.x] = W1[threadIdx.x];
    if (threadIdx.x < 16) sb[threadIdx.x] = b1[threadIdx.x];
    __syncthreads();
    int i = blockIdx.x * blockDim.x + threadIdx.x;
    if (i > N) return;
    uint4* gp = (uint4*)(g + (size_t)i * 16);   // 32B row
    if (i == N) {
        uint4 z = {0u, 0u, 0u, 0u};
        gp[0] = z; gp[1] = z;
        return;
    }
    float di = dinv[i];
    const float4* a4 = (const float4*)(agg8 + (size_t)i * 8);
    float4 v0 = a4[0], v1 = a4[1];
    float a[5] = {v0.x, v0.y, v0.z, v0.w, v1.x};
    union { __half h[16]; uint4 u[2]; } pk;
#pragma unroll
    for (int kk = 0; kk < 16; ++kk) {
        float h = 0.f;
#pragma unroll
        for (int d = 0; d < 5; ++d) h = fmaf(a[d], sW[d * 16 + kk], h);
        h = fmaxf(fmaf(di, h, sb[kk]), 0.f);
        pk.h[kk] = __float2half(h * di);
    }
    gp[0] = pk.u[0];
    gp[1] = pk.u[1];
}

// TWO nodes per wave (32 lanes each). Per half: lane k4 in [0,4) owns feature
// QUAD (4k4..4k4+3) via one 8B uint2 load (2x half2); j in [0,8) slots;
// depth 4 -> 32 edges per round at 8 VMEM ops/lane (half of v21). Tail slots
// clamp to zeroed row N. Reduce: xor 4,8,16 (stays within the half).
__global__ void k_gather16(const int* __restrict__ rowp, const int* __restrict__ srt,
                           const __half* __restrict__ g, float* __restrict__ agg16, int N) {
    int wv = (blockIdx.x * blockDim.x + threadIdx.x) >> 6;
    int lane = threadIdx.x & 63;
    int hl = lane & 31;
    int node = wv * 2 + (lane >> 5);
    if (node >= N) return;
    int k4 = hl & 3, j = hl >> 2;
    int b = node >> 8, dl = node & 255;
    int base = b * RPB + dl;
    int p0 = rowp[base], p1 = rowp[base + 1];
    const uint2* gq = (const uint2*)g;          // row = 4 uint2s (8B each)
    float ax = 0.f, ay = 0.f, az = 0.f, aw = 0.f;
    int p = p0 + j;
    while (p < p1) {
        int s0 = __builtin_nontemporal_load(srt + p);
        int s1 = __builtin_nontemporal_load(srt + p + 8);
        int s2 = __builtin_nontemporal_load(srt + p + 16);
        int s3 = __builtin_nontemporal_load(srt + p + 24);
        s1 = (p + 8  < p1) ? s1 : N;
        s2 = (p + 16 < p1) ? s2 : N;
        s3 = (p + 24 < p1) ? s3 : N;
        uint2 u0 = gq[(size_t)s0 * 4 + k4];
        uint2 u1 = gq[(size_t)s1 * 4 + k4];
        uint2 u2 = gq[(size_t)s2 * 4 + k4];
        uint2 u3 = gq[(size_t)s3 * 4 + k4];
        float2 a0 = __half22float2(*(const __half2*)&u0.x), b0 = __half22float2(*(const __half2*)&u0.y);
        float2 a1 = __half22float2(*(const __half2*)&u1.x), b1_ = __half22float2(*(const __half2*)&u1.y);
        float2 a2 = __half22float2(*(const __half2*)&u2.x), b2_ = __half22float2(*(const __half2*)&u2.y);
        float2 a3 = __half22float2(*(const __half2*)&u3.x), b3_ = __half22float2(*(const __half2*)&u3.y);
        ax += (a0.x + a1.x) + (a2.x + a3.x);
        ay += (a0.y + a1.y) + (a2.y + a3.y);
        az += (b0.x + b1_.x) + (b2_.x + b3_.x);
        aw += (b0.y + b1_.y) + (b2_.y + b3_.y);
        p += 32;
    }
    ax += __shfl_xor(ax, 4, 64);
    ax += __shfl_xor(ax, 8, 64);
    ax += __shfl_xor(ax, 16, 64);
    ay += __shfl_xor(ay, 4, 64);
    ay += __shfl_xor(ay, 8, 64);
    ay += __shfl_xor(ay, 16, 64);
    az += __shfl_xor(az, 4, 64);
    az += __shfl_xor(az, 8, 64);
    az += __shfl_xor(az, 16, 64);
    aw += __shfl_xor(aw, 4, 64);
    aw += __shfl_xor(aw, 8, 64);
    aw += __shfl_xor(aw, 16, 64);
    if (hl < 4) {
        uint2 us = gq[(size_t)node * 4 + k4];   // self-loop
        float2 s01 = __half22float2(*(const __half2*)&us.x);
        float2 s23 = __half22float2(*(const __half2*)&us.y);
        float4 o;
        o.x = ax + s01.x; o.y = ay + s01.y;
        o.z = az + s23.x; o.w = aw + s23.y;
        *(float4*)(agg16 + (size_t)node * 16 + 4 * k4) = o;
    }
}

// h2 = relu(dinv*(agg16@W2) + b2); c = h2 . fcW; spread-8 pool atomics
__global__ void k_fin(const float* __restrict__ agg16, const float* __restrict__ dinv,
                      const float* __restrict__ W2, const float* __restrict__ b2,
                      const float* __restrict__ fcW, const int* __restrict__ batch,
                      float* __restrict__ pool, int* __restrict__ gcnt, int N, int G) {
    __shared__ float sW[512], sb[32], sf[32];
    for (int t = threadIdx.x; t < 512; t += blockDim.x) sW[t] = W2[t];
    if (threadIdx.x < 32) {
        sb[threadIdx.x] = b2[threadIdx.x];
        sf[threadIdx.x] = fcW[threadIdx.x];
    }
    __syncthreads();
    int i = blockIdx.x * blockDim.x + threadIdx.x;
    if (i >= N) return;
    float di = dinv[i];
    float a[16];
    const float4* a4 = (const float4*)(agg16 + (size_t)i * 16);
#pragma unroll
    for (int q = 0; q < 4; ++q) {
        float4 v = a4[q];
        a[q * 4 + 0] = v.x; a[q * 4 + 1] = v.y; a[q * 4 + 2] = v.z; a[q * 4 + 3] = v.w;
    }
    float c = 0.f;
#pragma unroll
    for (int jj = 0; jj < 32; ++jj) {
        float acc2 = 0.f;
#pragma unroll
        for (int kk = 0; kk < 16; ++kk) acc2 = fmaf(a[kk], sW[kk * 32 + jj], acc2);
        float h = fmaxf(fmaf(di, acc2, sb[jj]), 0.f);
        c = fmaf(h, sf[jj], c);
    }
    int bidx = batch[i];
    int slot = i & (PSPREAD - 1);
    atomicAdd(&pool[slot * G + bidx], c);
    atomicAdd(&gcnt[slot * G + bidx], 1);
}

__global__ void k_out(const float* __restrict__ pool, const int* __restrict__ gcnt,
                      const float* __restrict__ fcb, float* __restrict__ out, int G) {
    int gI = blockIdx.x * blockDim.x + threadIdx.x;
    if (gI >= G) return;
    float s = 0.f; int c = 0;
#pragma unroll
    for (int k = 0; k < PSPREAD; ++k) { s += pool[k * G + gI]; c += gcnt[k * G + gI]; }
    out[gI] = s / fmaxf((float)c, 1.f) + fcb[0];
}

extern "C" void kernel_launch(void* const* d_in, const int* in_sizes, int n_in,
                              void* d_out, int out_size, void* d_ws, size_t ws_size,
                              hipStream_t stream) {
    const float* x    = (const float*)d_in[0];
    const int*   ei   = (const int*)d_in[1];
    const int*   batch= (const int*)d_in[2];
    const float* W1   = (const float*)d_in[3];
    const float* b1   = (const float*)d_in[4];
    const float* W2   = (const float*)d_in[5];
    const float* b2   = (const float*)d_in[6];
    const float* fcW  = (const float*)d_in[7];
    const float* fcb  = (const float*)d_in[8];
    float* out = (float*)d_out;

    const int N = in_sizes[0] / 5;
    const int E = in_sizes[1] / 2;
    const int G = out_size;  // 1024
    const int chunk = (E + NBLK - 1) / NBLK;  // 6250 <= CHUNKMAX

    const int* src = ei;
    const int* dst = ei + E;

    // workspace carve, every buffer 256B-aligned
    char* ws = (char*)d_ws;
    size_t o = 0;
    auto carve = [&](size_t bytes) -> char* {
        char* p = ws + o;
        o += (bytes + 255) & ~(size_t)255;
        return p;
    };
    int*    bfill   = (int*)carve((size_t)4 * NB);
    int*    rowp    = (int*)carve((size_t)4 * (NB * RPB + 4));
    float*  dinv    = (float*)carve((size_t)4 * N);
    __half* sx8     = (__half*)carve((size_t)16 * (N + 1));      // fp16 rows + zero row
    float*  agg8    = (float*)carve((size_t)32 * N);             // 3.2 MB
    int*    srt     = (int*)carve((size_t)4 * NB * CAP + 256);   // 16 MB + pad
    char*   rbase   = carve((size_t)4 * NB * CAP);               // 16 MB
    // blkcnt/base alias srt (dead before k_sort writes srt)
    int*    blkcnt  = srt;                                       // [NBLK][NB]
    int*    base    = srt + (size_t)NBLK * NB;                   // [NB][NBLK]
    unsigned int* recbuf = (unsigned int*)rbase;                 // dead after k_sort
    __half* g       = (__half*)rbase;                            // (N+1) x 16 halves, post-k_sort
    float*  agg16   = (float*)(rbase + (((size_t)32 * (N + 1) + 255) & ~(size_t)255)); // N x 16 f32
    float*  pool    = (float*)carve((size_t)4 * PSPREAD * G);
    int*    gcnt    = (int*)carve((size_t)4 * PSPREAD * G);      // contiguous with pool

    const int nz = 2 * PSPREAD * G;   // pool + gcnt ints, zeroed in k_cnt

    k_cnt<<<NBLK, 256, 0, stream>>>(dst, E, chunk, blkcnt, (int*)pool, nz);
    k_scanb<<<NB, 512, 0, stream>>>(blkcnt, base, bfill);
    k_scat<<<NBLK, 512, 0, stream>>>(src, dst, E, chunk, base, recbuf);
    k_sort<<<NB, 512, 0, stream>>>(bfill, recbuf, rowp, srt, x, dinv, sx8, N);
    {
        long long waves = (N + 1) / 2;
        int blocks = (int)((waves * 64 + 255) / 256);
        k_gather8<<<blocks, 256, 0, stream>>>(rowp, srt, sx8, agg8, N);
    }
    k_lin1<<<(N + 256) / 256, 256, 0, stream>>>(agg8, dinv, W1, b1, g, N);
    {
        long long waves = (N + 1) / 2;
        int blocks = (int)((waves * 64 + 255) / 256);
        k_gather16<<<blocks, 256, 0, stream>>>(rowp, srt, g, agg16, N);
    }
    k_fin<<<(N + 255) / 256, 256, 0, stream>>>(agg16, dinv, W2, b2, fcW, batch, pool, gcnt, N, G);
    k_out<<<(G + 255) / 256, 256, 0, stream>>>(pool, gcnt, fcb, out, G);
}